// Round 9
// baseline (80.440 us; speedup 1.0000x reference)
//
#include <hip/hip_runtime.h>
#include <hip/hip_bf16.h>

// AgentModel: B=8, N=256, TD=128, LH=128, H=128, A=5, L=2
constexpr int Nc = 256;
constexpr int Hc = 128;
constexpr int Ac = 5;
constexpr int Mc = 2048;
constexpr int R = 8;  // rows per block; grid = 256 = 1 block/CU

// async global->LDS, 16B per lane. dest must be wave-uniform base (HW adds
// lane*16); src is per-lane.
__device__ __forceinline__ void glds16(const float* g, float* l) {
  __builtin_amdgcn_global_load_lds(
      (const __attribute__((address_space(1))) void*)g,
      (__attribute__((address_space(3))) void*)l, 16, 0, 0);
}

// ---------------------------------------------------------------------------
// K1: encoder + pj/pi of layer 0.  256 blocks x 512 threads.
// ---------------------------------------------------------------------------
__global__ __launch_bounds__(512) void k1_enc_pjpi(
    const float* __restrict__ theta, const float* __restrict__ cell,
    const float* __restrict__ encW, const float* __restrict__ encb,
    const float* __restrict__ msgW0, float* __restrict__ h,
    float* __restrict__ pj, float* __restrict__ pi) {
  __shared__ float xs[R][256];
  __shared__ float hs[R][Hc];
  const int m0 = blockIdx.x * R;
  const int tid = threadIdx.x;

  {  // stage x = [theta|cell]: 512 threads x float4 = 2048 = 8*256 exactly
    int idx = tid * 4, r = idx >> 8, d = idx & 255;
    const float* src = (d < 128) ? theta + (m0 + r) * 128 + d
                                 : cell + (m0 + r) * 128 + (d - 128);
    *reinterpret_cast<float4*>(&xs[r][d]) = *reinterpret_cast<const float4*>(src);
  }
  __syncthreads();

  const int o = tid & 127;
  const int rg = tid >> 7;  // 0..3 -> rows rg*2, rg*2+1
  {                         // encoder
    const int r0 = rg * 2;
    float a0 = 0.f, a1 = 0.f;
    const float* wr = encW + o * 256;
#pragma unroll 8
    for (int k = 0; k < 256; k += 4) {
      float4 w = *reinterpret_cast<const float4*>(wr + k);
      a0 += w.x * xs[r0][k] + w.y * xs[r0][k + 1] + w.z * xs[r0][k + 2] +
            w.w * xs[r0][k + 3];
      a1 += w.x * xs[r0 + 1][k] + w.y * xs[r0 + 1][k + 1] +
            w.z * xs[r0 + 1][k + 2] + w.w * xs[r0 + 1][k + 3];
    }
    float b = encb[o];
    float v0 = fmaxf(a0 + b, 0.f), v1 = fmaxf(a1 + b, 0.f);
    hs[r0][o] = v0;
    hs[r0 + 1][o] = v1;
    h[(m0 + r0) * Hc + o] = v0;
    h[(m0 + r0 + 1) * Hc + o] = v1;
  }
  __syncthreads();

  {  // pj/pi layer 0: 256 cols x 2 rowgroups of 4 rows
    const int c = tid & 255;
    const int rg2 = tid >> 8;  // 0..1
    const int r0 = rg2 * 4;
    const float* wr = msgW0 + (c & 127) * 256 + ((c >> 7) << 7);
    float a[4] = {0.f, 0.f, 0.f, 0.f};
#pragma unroll 8
    for (int k = 0; k < 128; k += 4) {
      float4 w = *reinterpret_cast<const float4*>(wr + k);
#pragma unroll
      for (int r = 0; r < 4; ++r)
        a[r] += w.x * hs[r0 + r][k] + w.y * hs[r0 + r][k + 1] +
                w.z * hs[r0 + r][k + 2] + w.w * hs[r0 + r][k + 3];
    }
    float* dst = (c < 128) ? pj : pi;
    const int oc = c & 127;
#pragma unroll
    for (int r = 0; r < 4; ++r) dst[(m0 + r0 + r) * Hc + oc] = a[r];
  }
}

// ---------------------------------------------------------------------------
// K2/K3: agg(l)+upd(l) [+ pjpi(l+1) | + head]
// agg: DMA-stage the batch's pj slice into LDS in two 64KB chunks
// (global_load_lds, all loads in flight), consume at LDS speed.
// sum_j relu(v+s) = 0.5*(sum v + 256*s + sum|v+s|).
// smem (64KB) is reused after agg as xs/hs/zs scratch.
// ---------------------------------------------------------------------------
template <bool LAST>
__global__ __launch_bounds__(512) void k_layer(
    const float* __restrict__ pj, const float* __restrict__ pi,
    const float* __restrict__ mb, float* __restrict__ h,
    const float* __restrict__ updWl, const float* __restrict__ updbl,
    const float* __restrict__ msgW2, float* __restrict__ pj2,
    float* __restrict__ pi2, const float* __restrict__ hW1,
    const float* __restrict__ hb1, const float* __restrict__ hW2,
    const float* __restrict__ hb2, float* __restrict__ out) {
  __shared__ float smem[16384];  // 64 KB: pj chunk [128][128]; later xs/hs/zs
  const int m0 = blockIdx.x * R;
  const int b = m0 >> 8;
  const int tid = threadIdx.x;
  const int wave = tid >> 6;
  const int lane = tid & 63;
  const int o = tid & 127;
  const int rg = tid >> 7;  // 0..3 -> rows rg*2, rg*2+1
  const int r0 = rg * 2;
  const float* pjb = pj + b * Nc * Hc;

  // ---- issue DMA for chunk 0 (j = 0..127) immediately ----
#pragma unroll
  for (int rnd = 0; rnd < 8; ++rnd) {
    int off = rnd * 2048 + wave * 256;
    glds16(pjb + off + lane * 4, smem + off);
  }

  // ---- register preloads (fly under the DMA) ----
  const float mbo = mb[o];
  float s0 = pi[(m0 + r0) * Hc + o] + mbo;
  float s1 = pi[(m0 + r0 + 1) * Hc + o] + mbo;
  float dj0 = pj[(m0 + r0) * Hc + o];
  float dj1 = pj[(m0 + r0 + 1) * Hc + o];
  float h0 = h[(m0 + r0) * Hc + o];
  float h1 = h[(m0 + r0 + 1) * Hc + o];

  float vsum = 0.f, ab0 = 0.f, ab1 = 0.f;
  // ---- chunk 0 ----
  asm volatile("s_waitcnt vmcnt(0)" ::: "memory");
  __syncthreads();
#pragma unroll 8
  for (int j = 0; j < 128; ++j) {
    float v = smem[j * 128 + o];
    vsum += v;
    ab0 += fabsf(v + s0);
    ab1 += fabsf(v + s1);
  }
  __syncthreads();
  // ---- chunk 1 (j = 128..255) ----
#pragma unroll
  for (int rnd = 0; rnd < 8; ++rnd) {
    int off = rnd * 2048 + wave * 256;
    glds16(pjb + 16384 + off + lane * 4, smem + off);
  }
  asm volatile("s_waitcnt vmcnt(0)" ::: "memory");
  __syncthreads();
#pragma unroll 8
  for (int j = 0; j < 128; ++j) {
    float v = smem[j * 128 + o];
    vsum += v;
    ab0 += fabsf(v + s0);
    ab1 += fabsf(v + s1);
  }
  __syncthreads();  // chunk data consumed; smem free for reuse

  // ---- combine + write xs = h + agg ----
  float* xs = smem;          // [8][128]
  float* hsm = smem + 1024;  // [8][128]
  float* zs = smem + 2048;   // [8][128] (LAST only)
  {
    float d0 = fmaxf(dj0 + s0, 0.f);
    float d1 = fmaxf(dj1 + s1, 0.f);
    float sr0 = 0.5f * (vsum + 256.f * s0 + ab0);
    float sr1 = 0.5f * (vsum + 256.f * s1 + ab1);
    xs[r0 * 128 + o] = h0 + (sr0 - d0) * (1.f / 255.f);
    xs[(r0 + 1) * 128 + o] = h1 + (sr1 - d1) * (1.f / 255.f);
  }
  __syncthreads();

  {  // ---- update GEMM ----
    float a0 = 0.f, a1 = 0.f;
    const float* wr = updWl + o * Hc;
#pragma unroll 8
    for (int k = 0; k < 128; k += 4) {
      float4 w = *reinterpret_cast<const float4*>(wr + k);
      const float* x0 = xs + r0 * 128 + k;
      const float* x1 = xs + (r0 + 1) * 128 + k;
      a0 += w.x * x0[0] + w.y * x0[1] + w.z * x0[2] + w.w * x0[3];
      a1 += w.x * x1[0] + w.y * x1[1] + w.z * x1[2] + w.w * x1[3];
    }
    float bo = updbl[o];
    float v0 = fmaxf(a0 + bo, 0.f), v1 = fmaxf(a1 + bo, 0.f);
    hsm[r0 * 128 + o] = v0;
    hsm[(r0 + 1) * 128 + o] = v1;
    if (!LAST) {
      h[(m0 + r0) * Hc + o] = v0;
      h[(m0 + r0 + 1) * Hc + o] = v1;
    }
  }
  __syncthreads();

  if (!LAST) {  // ---- pj/pi next layer ----
    const int c = tid & 255;
    const int rg2 = tid >> 8;
    const int rr0 = rg2 * 4;
    const float* wr = msgW2 + (c & 127) * 256 + ((c >> 7) << 7);
    float a[4] = {0.f, 0.f, 0.f, 0.f};
#pragma unroll 8
    for (int k = 0; k < 128; k += 4) {
      float4 w = *reinterpret_cast<const float4*>(wr + k);
#pragma unroll
      for (int r = 0; r < 4; ++r) {
        const float* x = hsm + (rr0 + r) * 128 + k;
        a[r] += w.x * x[0] + w.y * x[1] + w.z * x[2] + w.w * x[3];
      }
    }
    float* dst = (c < 128) ? pj2 : pi2;
    const int oc = c & 127;
#pragma unroll
    for (int r = 0; r < 4; ++r) dst[(m0 + rr0 + r) * Hc + oc] = a[r];
  } else {  // ---- head ----
    float a0 = 0.f, a1 = 0.f;
    const float* wr = hW1 + o * Hc;
#pragma unroll 8
    for (int k = 0; k < 128; k += 4) {
      float4 w = *reinterpret_cast<const float4*>(wr + k);
      const float* x0 = hsm + r0 * 128 + k;
      const float* x1 = hsm + (r0 + 1) * 128 + k;
      a0 += w.x * x0[0] + w.y * x0[1] + w.z * x0[2] + w.w * x0[3];
      a1 += w.x * x1[0] + w.y * x1[1] + w.z * x1[2] + w.w * x1[3];
    }
    float bo = hb1[o];
    zs[r0 * 128 + o] = fmaxf(a0 + bo, 0.f);
    zs[(r0 + 1) * 128 + o] = fmaxf(a1 + bo, 0.f);
    __syncthreads();

    if (tid < R * Ac) {  // 40 dots of length 128
      const int r = tid / Ac;
      const int a = tid % Ac;
      const float* wr2 = hW2 + a * Hc;
      float sacc = 0.f;
#pragma unroll 8
      for (int k = 0; k < 128; k += 4) {
        float4 w = *reinterpret_cast<const float4*>(wr2 + k);
        const float* z = zs + r * 128 + k;
        sacc += w.x * z[0] + w.y * z[1] + w.z * z[2] + w.w * z[3];
      }
      out[(m0 + r) * Ac + a] = sacc + hb2[a];
    }
  }
}

// ---------------------------------------------------------------------------
extern "C" void kernel_launch(void* const* d_in, const int* in_sizes, int n_in,
                              void* d_out, int out_size, void* d_ws, size_t ws_size,
                              hipStream_t stream) {
  const float* theta = (const float*)d_in[0];
  const float* cell  = (const float*)d_in[1];
  const float* encW  = (const float*)d_in[2];
  const float* encb  = (const float*)d_in[3];
  const float* msgW  = (const float*)d_in[4];   // (2,128,256)
  const float* msgb  = (const float*)d_in[5];   // (2,128)
  const float* updW  = (const float*)d_in[6];   // (2,128,128)
  const float* updb  = (const float*)d_in[7];   // (2,128)
  const float* hW1   = (const float*)d_in[8];
  const float* hb1   = (const float*)d_in[9];
  const float* hW2   = (const float*)d_in[10];
  const float* hb2   = (const float*)d_in[11];
  float* out = (float*)d_out;

  float* ws = (float*)d_ws;
  const int MH = Mc * Hc;  // 262144
  float* h   = ws;
  float* pjA = ws + MH;
  float* piA = ws + 2 * MH;
  float* pjB = ws + 3 * MH;
  float* piB = ws + 4 * MH;

  const int grid = Mc / R;  // 256
  k1_enc_pjpi<<<grid, 512, 0, stream>>>(theta, cell, encW, encb, msgW, h, pjA,
                                        piA);
  k_layer<false><<<grid, 512, 0, stream>>>(pjA, piA, msgb, h, updW, updb,
                                           msgW + 32768, pjB, piB, hW1, hb1,
                                           hW2, hb2, out);
  k_layer<true><<<grid, 512, 0, stream>>>(pjB, piB, msgb + Hc, h, updW + 16384,
                                          updb + Hc, nullptr, nullptr, nullptr,
                                          hW1, hb1, hW2, hb2, out);
}